// Round 1
// baseline (354.300 us; speedup 1.0000x reference)
//
#include <hip/hip_runtime.h>
#include <hip/hip_bf16.h>
#include <math.h>

#define N_ROWS 8192
#define DIM 512
#define INV_TAU 5.0f
#define EXP5 148.41315910257660342f   // exp(1/tau) = exp(5)

typedef float f32x4 __attribute__((ext_vector_type(4)));
typedef __bf16 bf16x8 __attribute__((ext_vector_type(8)));

__device__ __forceinline__ void gload_lds16(const void* g, void* l) {
  __builtin_amdgcn_global_load_lds(
      (__attribute__((address_space(1))) void*)(void*)g,
      (__attribute__((address_space(3))) void*)l,
      16, 0, 0);
}

// One block per row: compute L2 norms of z1,z2 row, the fp32 diag dot, and
// write bf16 normalized h1,h2.
__global__ __launch_bounds__(256) void normalize_kernel(
    const float* __restrict__ z1, const float* __restrict__ z2,
    __hip_bfloat16* __restrict__ h1, __hip_bfloat16* __restrict__ h2,
    float* __restrict__ dvec) {
  const int row = blockIdx.x;
  const int t = threadIdx.x;
  const float* p1 = z1 + (size_t)row * DIM;
  const float* p2 = z2 + (size_t)row * DIM;
  float a0 = p1[t], a1 = p1[t + 256];
  float b0 = p2[t], b1 = p2[t + 256];
  float s1 = a0 * a0 + a1 * a1;
  float s2 = b0 * b0 + b1 * b1;
  float s3 = a0 * b0 + a1 * b1;
  for (int m = 32; m; m >>= 1) {
    s1 += __shfl_xor(s1, m);
    s2 += __shfl_xor(s2, m);
    s3 += __shfl_xor(s3, m);
  }
  __shared__ float red[3][4];
  const int wave = t >> 6;
  if ((t & 63) == 0) { red[0][wave] = s1; red[1][wave] = s2; red[2][wave] = s3; }
  __syncthreads();
  const float S1 = red[0][0] + red[0][1] + red[0][2] + red[0][3];
  const float S2 = red[1][0] + red[1][1] + red[1][2] + red[1][3];
  const float S3 = red[2][0] + red[2][1] + red[2][2] + red[2][3];
  const float n1 = fmaxf(sqrtf(S1), 1e-12f);
  const float n2 = fmaxf(sqrtf(S2), 1e-12f);
  const float inv1 = 1.0f / n1;
  const float inv2 = 1.0f / n2;
  __hip_bfloat16* o1 = h1 + (size_t)row * DIM;
  __hip_bfloat16* o2 = h2 + (size_t)row * DIM;
  o1[t] = __float2bfloat16(a0 * inv1);
  o1[t + 256] = __float2bfloat16(a1 * inv1);
  o2[t] = __float2bfloat16(b0 * inv2);
  o2[t + 256] = __float2bfloat16(b1 * inv2);
  if (t == 0) dvec[row] = S3 * inv1 * inv2;
}

// grid (64,64,3): z=0 -> exp(h1 h1^T) row sums into r1
//                 z=1 -> exp(h2 h2^T) row sums into r2
//                 z=2 -> exp(h1 h2^T) row sums into brow, col sums into bcol
// 128x128 tile per block, 4 waves (2x2), 4x4 frags of 16x16x32 bf16 MFMA.
__global__ __launch_bounds__(256) void expsum_kernel(
    const __hip_bfloat16* __restrict__ h1, const __hip_bfloat16* __restrict__ h2,
    float* __restrict__ r1, float* __restrict__ r2,
    float* __restrict__ brow, float* __restrict__ bcol) {
  __shared__ __align__(16) __hip_bfloat16 As[128 * 32];
  __shared__ __align__(16) __hip_bfloat16 Bs[128 * 32];
  __shared__ float lds_row[128];
  __shared__ float lds_col[128];

  const int z = blockIdx.z;
  const __hip_bfloat16* Ag = (z == 1) ? h2 : h1;
  const __hip_bfloat16* Bg = (z == 0) ? h1 : h2;
  const int i0 = blockIdx.x * 128;
  const int j0 = blockIdx.y * 128;

  const int t = threadIdx.x;
  const int wave = t >> 6;
  const int lane = t & 63;
  const int wm = wave >> 1;    // 0..1: row half of tile
  const int wn = wave & 1;     // 0..1: col half of tile
  const int l16 = lane & 15;
  const int kq = lane >> 4;    // 0..3

  // staging: LDS is row-major [128][32] bf16; thread t covers bytes
  // q*4096 + t*16 (q=0,1) -> row q*64 + t/4, k-offset (t&3)*8 elems.
  const int srow = t >> 2;
  const int skoff = (t & 3) * 8;
  const size_t abase0 = (size_t)(i0 + srow) * DIM + skoff;
  const size_t abase1 = (size_t)(i0 + 64 + srow) * DIM + skoff;
  const size_t bbase0 = (size_t)(j0 + srow) * DIM + skoff;
  const size_t bbase1 = (size_t)(j0 + 64 + srow) * DIM + skoff;
  char* AsB = (char*)As;
  char* BsB = (char*)Bs;
  const int wbase = wave * 1024;  // wave-uniform LDS base within a 4096B round

  f32x4 acc[4][4];
#pragma unroll
  for (int a = 0; a < 4; a++)
#pragma unroll
    for (int b = 0; b < 4; b++)
#pragma unroll
      for (int r = 0; r < 4; r++) acc[a][b][r] = 0.0f;

  for (int kb = 0; kb < DIM / 32; kb++) {
    const int k0 = kb * 32;
    gload_lds16(Ag + abase0 + k0, AsB + wbase);
    gload_lds16(Ag + abase1 + k0, AsB + 4096 + wbase);
    gload_lds16(Bg + bbase0 + k0, BsB + wbase);
    gload_lds16(Bg + bbase1 + k0, BsB + 4096 + wbase);
    __syncthreads();

    bf16x8 afrag[4], bfrag[4];
#pragma unroll
    for (int f = 0; f < 4; f++) {
      afrag[f] = *(const bf16x8*)(AsB + ((wm * 64 + f * 16 + l16) * 32 + kq * 8) * 2);
      bfrag[f] = *(const bf16x8*)(BsB + ((wn * 64 + f * 16 + l16) * 32 + kq * 8) * 2);
    }
#pragma unroll
    for (int fm = 0; fm < 4; fm++)
#pragma unroll
      for (int fn = 0; fn < 4; fn++)
        acc[fm][fn] = __builtin_amdgcn_mfma_f32_16x16x32_bf16(
            afrag[fm], bfrag[fn], acc[fm][fn], 0, 0, 0);
    __syncthreads();
  }

  // Epilogue: e = exp(s/tau); C/D layout: col = lane&15, row = kq*4 + reg.
  float rowp[4][4];  // [fm][r] partial over this wave's 64 cols
  float colp[4];     // [fn]    partial over this wave's 64 rows
#pragma unroll
  for (int fm = 0; fm < 4; fm++)
#pragma unroll
    for (int r = 0; r < 4; r++) rowp[fm][r] = 0.0f;
#pragma unroll
  for (int fn = 0; fn < 4; fn++) colp[fn] = 0.0f;

#pragma unroll
  for (int fm = 0; fm < 4; fm++)
#pragma unroll
    for (int fn = 0; fn < 4; fn++)
#pragma unroll
      for (int r = 0; r < 4; r++) {
        const float e = __expf(acc[fm][fn][r] * INV_TAU);
        rowp[fm][r] += e;
        colp[fn] += e;
      }

  if (t < 128) lds_row[t] = 0.0f; else lds_col[t - 128] = 0.0f;
  __syncthreads();

  // Row sums: reduce across the 16 lanes (cols) sharing kq.
#pragma unroll
  for (int fm = 0; fm < 4; fm++) {
#pragma unroll
    for (int r = 0; r < 4; r++) {
      float v = rowp[fm][r];
      v += __shfl_xor(v, 1);
      v += __shfl_xor(v, 2);
      v += __shfl_xor(v, 4);
      v += __shfl_xor(v, 8);
      if (l16 == 0) atomicAdd(&lds_row[wm * 64 + fm * 16 + kq * 4 + r], v);
    }
  }
  // Col sums: reduce across the 4 kq groups (rows).
#pragma unroll
  for (int fn = 0; fn < 4; fn++) {
    float v = colp[fn];
    v += __shfl_xor(v, 16);
    v += __shfl_xor(v, 32);
    if (kq == 0) atomicAdd(&lds_col[wn * 64 + fn * 16 + l16], v);
  }
  __syncthreads();

  if (z == 0) {
    if (t < 128) atomicAdd(&r1[i0 + t], lds_row[t]);
  } else if (z == 1) {
    if (t < 128) atomicAdd(&r2[i0 + t], lds_row[t]);
  } else {
    if (t < 128) atomicAdd(&brow[i0 + t], lds_row[t]);
    else         atomicAdd(&bcol[j0 + (t - 128)], lds_col[t - 128]);
  }
}

__global__ __launch_bounds__(256) void finalize_kernel(
    const float* __restrict__ r1, const float* __restrict__ r2,
    const float* __restrict__ brow, const float* __restrict__ bcol,
    const float* __restrict__ dvec, float* __restrict__ out) {
  const int i = blockIdx.x * 256 + threadIdx.x;
  const float den1 = r1[i] + brow[i] - EXP5;
  const float den2 = r2[i] + bcol[i] - EXP5;
  float v = 0.5f * (logf(den1) + logf(den2)) - INV_TAU * dvec[i];
  for (int m = 32; m; m >>= 1) v += __shfl_xor(v, m);
  __shared__ float red[4];
  const int wave = threadIdx.x >> 6;
  if ((threadIdx.x & 63) == 0) red[wave] = v;
  __syncthreads();
  if (threadIdx.x == 0) atomicAdd(out, red[0] + red[1] + red[2] + red[3]);
}

extern "C" void kernel_launch(void* const* d_in, const int* in_sizes, int n_in,
                              void* d_out, int out_size, void* d_ws, size_t ws_size,
                              hipStream_t stream) {
  const float* z1 = (const float*)d_in[0];
  const float* z2 = (const float*)d_in[1];
  float* out = (float*)d_out;

  char* ws = (char*)d_ws;
  __hip_bfloat16* h1 = (__hip_bfloat16*)ws;                   // 8 MiB
  __hip_bfloat16* h2 = (__hip_bfloat16*)(ws + 8388608);       // 8 MiB
  float* r1   = (float*)(ws + 16777216);                      // 4 x 32 KiB sums
  float* r2   = r1 + N_ROWS;
  float* brow = r2 + N_ROWS;
  float* bcol = brow + N_ROWS;
  float* dvec = bcol + N_ROWS;                                // 32 KiB

  // ws/out are poisoned 0xAA before every timed launch — re-zero accumulators.
  hipMemsetAsync(r1, 0, 4 * N_ROWS * sizeof(float), stream);
  hipMemsetAsync(out, 0, sizeof(float), stream);

  normalize_kernel<<<N_ROWS, 256, 0, stream>>>(z1, z2, h1, h2, dvec);
  expsum_kernel<<<dim3(64, 64, 3), 256, 0, stream>>>(h1, h2, r1, r2, brow, bcol);
  finalize_kernel<<<N_ROWS / 256, 256, 0, stream>>>(r1, r2, brow, bcol, dvec, out);
}

// Round 2
// 314.310 us; speedup vs baseline: 1.1272x; 1.1272x over previous
//
#include <hip/hip_runtime.h>
#include <hip/hip_bf16.h>
#include <math.h>

#define N_ROWS 8192
#define DIM 512
#define INV_TAU 5.0f
#define EXP5 148.41315910257660342f   // exp(1/tau) = exp(5)

typedef float f32x4 __attribute__((ext_vector_type(4)));
typedef __bf16 bf16x8 __attribute__((ext_vector_type(8)));

__device__ __forceinline__ void gload_lds16(const void* g, void* l) {
  __builtin_amdgcn_global_load_lds(
      (__attribute__((address_space(1))) void*)(void*)g,
      (__attribute__((address_space(3))) void*)l,
      16, 0, 0);
}

// One block per row: compute L2 norms of z1,z2 row, the fp32 diag dot, and
// write bf16 normalized h1,h2.
__global__ __launch_bounds__(256) void normalize_kernel(
    const float* __restrict__ z1, const float* __restrict__ z2,
    __hip_bfloat16* __restrict__ h1, __hip_bfloat16* __restrict__ h2,
    float* __restrict__ dvec) {
  const int row = blockIdx.x;
  const int t = threadIdx.x;
  const float* p1 = z1 + (size_t)row * DIM;
  const float* p2 = z2 + (size_t)row * DIM;
  float a0 = p1[t], a1 = p1[t + 256];
  float b0 = p2[t], b1 = p2[t + 256];
  float s1 = a0 * a0 + a1 * a1;
  float s2 = b0 * b0 + b1 * b1;
  float s3 = a0 * b0 + a1 * b1;
  for (int m = 32; m; m >>= 1) {
    s1 += __shfl_xor(s1, m);
    s2 += __shfl_xor(s2, m);
    s3 += __shfl_xor(s3, m);
  }
  __shared__ float red[3][4];
  const int wave = t >> 6;
  if ((t & 63) == 0) { red[0][wave] = s1; red[1][wave] = s2; red[2][wave] = s3; }
  __syncthreads();
  const float S1 = red[0][0] + red[0][1] + red[0][2] + red[0][3];
  const float S2 = red[1][0] + red[1][1] + red[1][2] + red[1][3];
  const float S3 = red[2][0] + red[2][1] + red[2][2] + red[2][3];
  const float n1 = fmaxf(sqrtf(S1), 1e-12f);
  const float n2 = fmaxf(sqrtf(S2), 1e-12f);
  const float inv1 = 1.0f / n1;
  const float inv2 = 1.0f / n2;
  __hip_bfloat16* o1 = h1 + (size_t)row * DIM;
  __hip_bfloat16* o2 = h2 + (size_t)row * DIM;
  o1[t] = __float2bfloat16(a0 * inv1);
  o1[t + 256] = __float2bfloat16(a1 * inv1);
  o2[t] = __float2bfloat16(b0 * inv2);
  o2[t + 256] = __float2bfloat16(b1 * inv2);
  if (t == 0) dvec[row] = S3 * inv1 * inv2;
}

// grid (64,64,3):
//   z=0 -> exp(h1 h1^T): SYMMETRIC — only blocks with j0>=i0 run. Off-diag
//          blocks add row sums to r1[i0..] AND col sums to r1[j0..]; diagonal
//          blocks add row sums only.
//   z=1 -> same for exp(h2 h2^T) into r2.
//   z=2 -> exp(h1 h2^T): full grid; row sums -> brow[i0..], col sums -> bcol[j0..].
// 128x128 tile per block, 4 waves (2x2), 4x4 frags of 16x16x32 bf16 MFMA.
__global__ __launch_bounds__(256) void expsum_kernel(
    const __hip_bfloat16* __restrict__ h1, const __hip_bfloat16* __restrict__ h2,
    float* __restrict__ r1, float* __restrict__ r2,
    float* __restrict__ brow, float* __restrict__ bcol) {
  const int z = blockIdx.z;
  const int i0 = blockIdx.x * 128;
  const int j0 = blockIdx.y * 128;
  if (z != 2 && j0 < i0) return;  // symmetric: lower triangle handled by upper
  const bool diag = (z != 2) && (i0 == j0);

  __shared__ __align__(16) __hip_bfloat16 As[128 * 32];
  __shared__ __align__(16) __hip_bfloat16 Bs[128 * 32];
  __shared__ float lds_row[128];
  __shared__ float lds_col[128];

  const __hip_bfloat16* Ag = (z == 1) ? h2 : h1;
  const __hip_bfloat16* Bg = (z == 0) ? h1 : h2;

  const int t = threadIdx.x;
  const int wave = t >> 6;
  const int lane = t & 63;
  const int wm = wave >> 1;    // 0..1: row half of tile
  const int wn = wave & 1;     // 0..1: col half of tile
  const int l16 = lane & 15;
  const int kq = lane >> 4;    // 0..3

  // staging: LDS is row-major [128][32] bf16; thread t covers bytes
  // q*4096 + t*16 (q=0,1) -> row q*64 + t/4, k-offset (t&3)*8 elems.
  const int srow = t >> 2;
  const int skoff = (t & 3) * 8;
  const size_t abase0 = (size_t)(i0 + srow) * DIM + skoff;
  const size_t abase1 = (size_t)(i0 + 64 + srow) * DIM + skoff;
  const size_t bbase0 = (size_t)(j0 + srow) * DIM + skoff;
  const size_t bbase1 = (size_t)(j0 + 64 + srow) * DIM + skoff;
  char* AsB = (char*)As;
  char* BsB = (char*)Bs;
  const int wbase = wave * 1024;  // wave-uniform LDS base within a 4096B round

  f32x4 acc[4][4];
#pragma unroll
  for (int a = 0; a < 4; a++)
#pragma unroll
    for (int b = 0; b < 4; b++)
#pragma unroll
      for (int r = 0; r < 4; r++) acc[a][b][r] = 0.0f;

  for (int kb = 0; kb < DIM / 32; kb++) {
    const int k0 = kb * 32;
    gload_lds16(Ag + abase0 + k0, AsB + wbase);
    gload_lds16(Ag + abase1 + k0, AsB + 4096 + wbase);
    gload_lds16(Bg + bbase0 + k0, BsB + wbase);
    gload_lds16(Bg + bbase1 + k0, BsB + 4096 + wbase);
    __syncthreads();

    bf16x8 afrag[4], bfrag[4];
#pragma unroll
    for (int f = 0; f < 4; f++) {
      afrag[f] = *(const bf16x8*)(AsB + ((wm * 64 + f * 16 + l16) * 32 + kq * 8) * 2);
      bfrag[f] = *(const bf16x8*)(BsB + ((wn * 64 + f * 16 + l16) * 32 + kq * 8) * 2);
    }
#pragma unroll
    for (int fm = 0; fm < 4; fm++)
#pragma unroll
      for (int fn = 0; fn < 4; fn++)
        acc[fm][fn] = __builtin_amdgcn_mfma_f32_16x16x32_bf16(
            afrag[fm], bfrag[fn], acc[fm][fn], 0, 0, 0);
    __syncthreads();
  }

  // Epilogue: e = exp(s/tau); C/D layout: col = lane&15, row = kq*4 + reg.
  float rowp[4][4];  // [fm][r] partial over this wave's 64 cols
  float colp[4];     // [fn]    partial over this wave's 64 rows
#pragma unroll
  for (int fm = 0; fm < 4; fm++)
#pragma unroll
    for (int r = 0; r < 4; r++) rowp[fm][r] = 0.0f;
#pragma unroll
  for (int fn = 0; fn < 4; fn++) colp[fn] = 0.0f;

#pragma unroll
  for (int fm = 0; fm < 4; fm++)
#pragma unroll
    for (int fn = 0; fn < 4; fn++)
#pragma unroll
      for (int r = 0; r < 4; r++) {
        const float e = __expf(acc[fm][fn][r] * INV_TAU);
        rowp[fm][r] += e;
        colp[fn] += e;
      }

  if (t < 128) lds_row[t] = 0.0f; else lds_col[t - 128] = 0.0f;
  __syncthreads();

  // Row sums: reduce across the 16 lanes (cols) sharing kq.
#pragma unroll
  for (int fm = 0; fm < 4; fm++) {
#pragma unroll
    for (int r = 0; r < 4; r++) {
      float v = rowp[fm][r];
      v += __shfl_xor(v, 1);
      v += __shfl_xor(v, 2);
      v += __shfl_xor(v, 4);
      v += __shfl_xor(v, 8);
      if (l16 == 0) atomicAdd(&lds_row[wm * 64 + fm * 16 + kq * 4 + r], v);
    }
  }
  // Col sums: reduce across the 4 kq groups (rows).
#pragma unroll
  for (int fn = 0; fn < 4; fn++) {
    float v = colp[fn];
    v += __shfl_xor(v, 16);
    v += __shfl_xor(v, 32);
    if (kq == 0) atomicAdd(&lds_col[wn * 64 + fn * 16 + l16], v);
  }
  __syncthreads();

  if (z == 2) {
    if (t < 128) atomicAdd(&brow[i0 + t], lds_row[t]);
    else         atomicAdd(&bcol[j0 + (t - 128)], lds_col[t - 128]);
  } else {
    float* r = (z == 0) ? r1 : r2;
    if (t < 128) atomicAdd(&r[i0 + t], lds_row[t]);
    else if (!diag) atomicAdd(&r[j0 + (t - 128)], lds_col[t - 128]);
  }
}

__global__ __launch_bounds__(256) void finalize_kernel(
    const float* __restrict__ r1, const float* __restrict__ r2,
    const float* __restrict__ brow, const float* __restrict__ bcol,
    const float* __restrict__ dvec, float* __restrict__ out) {
  const int i = blockIdx.x * 256 + threadIdx.x;
  const float den1 = r1[i] + brow[i] - EXP5;
  const float den2 = r2[i] + bcol[i] - EXP5;
  float v = 0.5f * (logf(den1) + logf(den2)) - INV_TAU * dvec[i];
  for (int m = 32; m; m >>= 1) v += __shfl_xor(v, m);
  __shared__ float red[4];
  const int wave = threadIdx.x >> 6;
  if ((threadIdx.x & 63) == 0) red[wave] = v;
  __syncthreads();
  if (threadIdx.x == 0) atomicAdd(out, red[0] + red[1] + red[2] + red[3]);
}

extern "C" void kernel_launch(void* const* d_in, const int* in_sizes, int n_in,
                              void* d_out, int out_size, void* d_ws, size_t ws_size,
                              hipStream_t stream) {
  const float* z1 = (const float*)d_in[0];
  const float* z2 = (const float*)d_in[1];
  float* out = (float*)d_out;

  char* ws = (char*)d_ws;
  __hip_bfloat16* h1 = (__hip_bfloat16*)ws;                   // 8 MiB
  __hip_bfloat16* h2 = (__hip_bfloat16*)(ws + 8388608);       // 8 MiB
  float* r1   = (float*)(ws + 16777216);                      // 4 x 32 KiB sums
  float* r2   = r1 + N_ROWS;
  float* brow = r2 + N_ROWS;
  float* bcol = brow + N_ROWS;
  float* dvec = bcol + N_ROWS;                                // 32 KiB

  // ws/out are poisoned 0xAA before every timed launch — re-zero accumulators.
  hipMemsetAsync(r1, 0, 4 * N_ROWS * sizeof(float), stream);
  hipMemsetAsync(out, 0, sizeof(float), stream);

  normalize_kernel<<<N_ROWS, 256, 0, stream>>>(z1, z2, h1, h2, dvec);
  expsum_kernel<<<dim3(64, 64, 3), 256, 0, stream>>>(h1, h2, r1, r2, brow, bcol);
  finalize_kernel<<<N_ROWS / 256, 256, 0, stream>>>(r1, r2, brow, bcol, dvec, out);
}